// Round 1
// baseline (560.327 us; speedup 1.0000x reference)
//
#include <hip/hip_runtime.h>
#include <math.h>

#define NV 204800
#define NE 409600
#define NG 512
#define V_PER 400
#define E_PER 800

// ---------------- Kernel 1: vertex MLP  fv = sigmoid(relu(x@W1+b1)@W2+b2) ---
__global__ __launch_bounds__(256, 2)
void k_vertex_mlp(const float* __restrict__ x, const float* __restrict__ W1,
                  const float* __restrict__ b1, const float* __restrict__ W2,
                  const float* __restrict__ b2, float* __restrict__ fv) {
  __shared__ float W1s[128 * 64];   // 32 KB
  __shared__ float xs[32][128];     // 16 KB
  __shared__ float hs[32][65];      // 8.45 KB (pad 65 breaks bank conflicts)
  __shared__ float W2s[64 * 8];
  __shared__ float b1s[64];
  __shared__ float b2s[8];
  const int tid = threadIdx.x;

  { // stage W1 (coalesced float4)
    const float4* s4 = (const float4*)W1;
    float4* d4 = (float4*)W1s;
    #pragma unroll
    for (int i = 0; i < 8; ++i) d4[tid + 256 * i] = s4[tid + 256 * i];
  }
  if (tid < 128) ((float4*)W2s)[tid] = ((const float4*)W2)[tid];
  if (tid < 64) b1s[tid] = b1[tid];
  if (tid < 8)  b2s[tid] = b2[tid];

  const long vb = (long)blockIdx.x * 32;
  { // stage x tile [32][128]
    const float4* s4 = (const float4*)(x + vb * 128);
    float4* d4 = (float4*)&xs[0][0];
    #pragma unroll
    for (int i = 0; i < 4; ++i) d4[tid + 256 * i] = s4[tid + 256 * i];
  }
  __syncthreads();

  // layer 1: each wave = 64 j-lanes, 4 waves each own 8 vertices
  const int j = tid & 63;
  const int vg = tid >> 6;
  float acc[8];
  #pragma unroll
  for (int v = 0; v < 8; ++v) acc[v] = b1s[j];
  #pragma unroll 4
  for (int k = 0; k < 128; ++k) {
    const float w = W1s[k * 64 + j];          // 2-way (free) LDS
    #pragma unroll
    for (int v = 0; v < 8; ++v) acc[v] = fmaf(xs[vg * 8 + v][k], w, acc[v]);  // broadcast
  }
  #pragma unroll
  for (int v = 0; v < 8; ++v) hs[vg * 8 + v][j] = fmaxf(acc[v], 0.0f);
  __syncthreads();

  // layer 2 + sigmoid: thread -> (vertex, out)
  const int v2 = tid >> 3;
  const int o = tid & 7;
  float a2 = b2s[o];
  #pragma unroll 8
  for (int jj = 0; jj < 64; ++jj) a2 = fmaf(hs[v2][jj], W2s[jj * 8 + o], a2);
  fv[(vb + v2) * 8 + o] = 1.0f / (1.0f + __expf(-a2));
}

// ---------------- Kernel 2: edge MLP  fe = sigmoid(relu(xe@We1+be1)@We2+be2) -
__global__ __launch_bounds__(256, 2)
void k_edge_mlp(const float* __restrict__ x, const float* __restrict__ pos,
                const int* __restrict__ srcp, const int* __restrict__ dstp,
                const float* __restrict__ We1, const float* __restrict__ be1,
                const float* __restrict__ We2, const float* __restrict__ be2,
                float* __restrict__ fe) {
  __shared__ float Ws[129 * 64];    // 33 KB
  __shared__ float xe[32][132];     // 16.9 KB (132 keeps rows 16B-aligned)
  __shared__ float hs[32][65];
  __shared__ float W2s[64 * 8];
  __shared__ float b1s[64];
  __shared__ float b2s[8];
  const int tid = threadIdx.x;

  // XCD-chunked swizzle: 12800 blocks = 8 * 1600; keep a graph's blocks on one XCD
  const int bid = blockIdx.x;
  const int lb = (bid & 7) * (NE / 32 / 8) + (bid >> 3);

  for (int i = tid; i < 129 * 64; i += 256) Ws[i] = We1[i];
  if (tid < 128) ((float4*)W2s)[tid] = ((const float4*)We2)[tid];
  if (tid < 64) b1s[tid] = be1[tid];
  if (tid < 8)  b2s[tid] = be2[tid];

  const int eb = lb * 32;
  { // gather xe = x[src]+x[dst] (8 threads per edge), dist in col 128
    const int e = tid >> 3;
    const int t8 = tid & 7;
    const int s = srcp[eb + e], d = dstp[eb + e];
    const float4* xs4 = (const float4*)(x + (long)s * 128);
    const float4* xd4 = (const float4*)(x + (long)d * 128);
    float4* row = (float4*)&xe[e][0];
    #pragma unroll
    for (int i = 0; i < 4; ++i) {
      float4 a = xs4[t8 * 4 + i];
      float4 b = xd4[t8 * 4 + i];
      row[t8 * 4 + i] = make_float4(a.x + b.x, a.y + b.y, a.z + b.z, a.w + b.w);
    }
    if (t8 == 0) {
      float dx = pos[s * 3 + 0] - pos[d * 3 + 0];
      float dy = pos[s * 3 + 1] - pos[d * 3 + 1];
      float dz = pos[s * 3 + 2] - pos[d * 3 + 2];
      xe[e][128] = sqrtf(dx * dx + dy * dy + dz * dz);
    }
  }
  __syncthreads();

  const int j = tid & 63;
  const int vg = tid >> 6;
  float acc[8];
  #pragma unroll
  for (int v = 0; v < 8; ++v) acc[v] = b1s[j];
  #pragma unroll 4
  for (int k = 0; k < 128; ++k) {
    const float w = Ws[k * 64 + j];
    #pragma unroll
    for (int v = 0; v < 8; ++v) acc[v] = fmaf(xe[vg * 8 + v][k], w, acc[v]);
  }
  { // k = 128 (distance feature)
    const float w = Ws[128 * 64 + j];
    #pragma unroll
    for (int v = 0; v < 8; ++v) acc[v] = fmaf(xe[vg * 8 + v][128], w, acc[v]);
  }
  #pragma unroll
  for (int v = 0; v < 8; ++v) hs[vg * 8 + v][j] = fmaxf(acc[v], 0.0f);
  __syncthreads();

  const int e2 = tid >> 3;
  const int o = tid & 7;
  float a2 = b2s[o];
  #pragma unroll 8
  for (int jj = 0; jj < 64; ++jj) a2 = fmaf(hs[e2][jj], W2s[jj * 8 + o], a2);
  fe[(long)(eb + e2) * 8 + o] = 1.0f / (1.0f + __expf(-a2));
}

// ------- Kernel 3: per-graph LDS scatter min/max + reduce + lin0 -> h -------
__global__ __launch_bounds__(256, 2)
void k_graph_reduce(const float* __restrict__ fv, const float* __restrict__ fe,
                    const int* __restrict__ srcp, const int* __restrict__ dstp,
                    const float* __restrict__ Wd0, const float* __restrict__ bd0,
                    const float* __restrict__ Wd1, const float* __restrict__ bd1,
                    float* __restrict__ hbuf) {
  __shared__ unsigned dminS[V_PER * 8];  // 12.8 KB
  __shared__ unsigned dmaxS[V_PER * 8];  // 12.8 KB
  __shared__ float red[256];
  __shared__ float sums[3][8];
  const int tid = threadIdx.x;
  const int g = blockIdx.x;

  for (int i = tid; i < V_PER * 8; i += 256) {
    dminS[i] = 0x7F800000u;  // +inf bits (fe > 0 so uint compare == float compare)
    dmaxS[i] = 0u;           // 0.0f bits
  }
  __syncthreads();

  const int eb = g * E_PER;
  const int vb = g * V_PER;
  for (int e = tid; e < E_PER; e += 256) {
    const int ls = srcp[eb + e] - vb;
    const int ld = dstp[eb + e] - vb;
    const uint4 f0 = ((const uint4*)(fe + (long)(eb + e) * 8))[0];
    const uint4 f1 = ((const uint4*)(fe + (long)(eb + e) * 8))[1];
    const unsigned fb[8] = {f0.x, f0.y, f0.z, f0.w, f1.x, f1.y, f1.z, f1.w};
    #pragma unroll
    for (int f = 0; f < 8; ++f) {
      atomicMin(&dminS[ls * 8 + f], fb[f]);
      atomicMax(&dmaxS[ls * 8 + f], fb[f]);
      atomicMin(&dminS[ld * 8 + f], fb[f]);
      atomicMax(&dmaxS[ld * 8 + f], fb[f]);
    }
  }
  __syncthreads();

  // per-f sums of fv, dmax, dmin (isolated vertices -> 1.0 both)
  const int f = tid & 7;
  float sfv = 0.f, smin = 0.f, smax = 0.f;
  for (int v = tid >> 3; v < V_PER; v += 32) {
    sfv += fv[(long)(vb + v) * 8 + f];
    const unsigned mn = dminS[v * 8 + f];
    if (mn == 0x7F800000u) { smin += 1.0f; smax += 1.0f; }
    else { smin += __uint_as_float(mn); smax += __uint_as_float(dmaxS[v * 8 + f]); }
  }
  // reduce within the 32 stride-8 threads sharing each f
  red[tid] = sfv; __syncthreads();
  for (int s = 128; s >= 8; s >>= 1) { if (tid < s) red[tid] += red[tid + s]; __syncthreads(); }
  if (tid < 8) sums[0][tid] = red[tid];
  __syncthreads();
  red[tid] = smax; __syncthreads();
  for (int s = 128; s >= 8; s >>= 1) { if (tid < s) red[tid] += red[tid + s]; __syncthreads(); }
  if (tid < 8) sums[1][tid] = red[tid];
  __syncthreads();
  red[tid] = smin; __syncthreads();
  for (int s = 128; s >= 8; s >>= 1) { if (tid < s) red[tid] += red[tid + s]; __syncthreads(); }
  if (tid < 8) sums[2][tid] = red[tid];
  __syncthreads();

  if (tid < 64) {
    const int o = tid;
    const float inv = 1.0f / (float)V_PER;
    float acc = bd0[o];
    #pragma unroll
    for (int ff = 0; ff < 8; ++ff) {
      acc = fmaf(sums[0][ff] * inv, Wd0[(4 * ff + 1) * 64 + o], acc);
      acc = fmaf(sums[1][ff] * inv, Wd0[(4 * ff + 2) * 64 + o], acc);
      acc = fmaf(sums[2][ff] * inv, Wd0[(4 * ff + 3) * 64 + o], acc);
    }
    // dim-1 branch is a constant: x1 = Wd1[1]+Wd1[2]+Wd1[3]+bd1 (every graph)
    const float x1 = Wd1[64 + o] + Wd1[128 + o] + Wd1[192 + o] + bd1[o];
    hbuf[g * 64 + o] = acc + x1;
  }
}

// ---------------- Kernel 4: BatchNorm stats over 512 graphs -----------------
__global__ __launch_bounds__(256)
void k_bn_stats(const float* __restrict__ hbuf, float* __restrict__ mu,
                float* __restrict__ rstd) {
  __shared__ float rs[256], rs2[256];
  const int tid = threadIdx.x;
  const int c = tid & 63, rg = tid >> 6;
  float s = 0.f, s2 = 0.f;
  for (int r = rg * 128; r < rg * 128 + 128; ++r) {
    const float v = hbuf[r * 64 + c];
    s += v; s2 += v * v;
  }
  rs[tid] = s; rs2[tid] = s2; __syncthreads();
  if (tid < 128) { rs[tid] += rs[tid + 128]; rs2[tid] += rs2[tid + 128]; }
  __syncthreads();
  if (tid < 64) {
    const float st = rs[tid] + rs[tid + 64];
    const float st2 = rs2[tid] + rs2[tid + 64];
    const float m = st / 512.0f;
    const float var = st2 / 512.0f - m * m;
    mu[tid] = m;
    rstd[tid] = rsqrtf(var + 1e-5f);
  }
}

// ---------------- Kernel 5: BN apply + out MLP ------------------------------
__global__ __launch_bounds__(256)
void k_out_mlp(const float* __restrict__ hbuf, const float* __restrict__ mu,
               const float* __restrict__ rstd, const float* __restrict__ gam,
               const float* __restrict__ bet, const float* __restrict__ Wo1,
               const float* __restrict__ bo1, const float* __restrict__ Wo2,
               const float* __restrict__ bo2, float* __restrict__ out) {
  __shared__ float W1s[64 * 64], W2s[64 * 64];
  __shared__ float hn[4][64], t1[4][64];
  __shared__ float mus[64], rstds[64], gs[64], bs[64], b1s[64], b2s[64];
  const int tid = threadIdx.x;
  for (int i = tid; i < 4096; i += 256) { W1s[i] = Wo1[i]; W2s[i] = Wo2[i]; }
  if (tid < 64) {
    mus[tid] = mu[tid]; rstds[tid] = rstd[tid]; gs[tid] = gam[tid];
    bs[tid] = bet[tid]; b1s[tid] = bo1[tid]; b2s[tid] = bo2[tid];
  }
  __syncthreads();
  const int r = tid >> 6, o = tid & 63;
  for (int it = 0; it < 4; ++it) {
    const int row = blockIdx.x * 16 + it * 4 + r;
    hn[r][o] = (hbuf[row * 64 + o] - mus[o]) * rstds[o] * gs[o] + bs[o];
    __syncthreads();
    float a = b1s[o];
    #pragma unroll 8
    for (int i = 0; i < 64; ++i) a = fmaf(hn[r][i], W1s[i * 64 + o], a);
    t1[r][o] = fmaxf(a, 0.f);
    __syncthreads();
    float a2 = b2s[o];
    #pragma unroll 8
    for (int i = 0; i < 64; ++i) a2 = fmaf(t1[r][i], W2s[i * 64 + o], a2);
    out[row * 64 + o] = a2;
    __syncthreads();
  }
}

extern "C" void kernel_launch(void* const* d_in, const int* in_sizes, int n_in,
                              void* d_out, int out_size, void* d_ws, size_t ws_size,
                              hipStream_t stream) {
  const float* x   = (const float*)d_in[0];
  const float* pos = (const float*)d_in[1];
  const int*   ei  = (const int*)d_in[2];
  const float* W1  = (const float*)d_in[6];
  const float* b1  = (const float*)d_in[7];
  const float* W2  = (const float*)d_in[8];
  const float* b2  = (const float*)d_in[9];
  const float* We1 = (const float*)d_in[10];
  const float* be1 = (const float*)d_in[11];
  const float* We2 = (const float*)d_in[12];
  const float* be2 = (const float*)d_in[13];
  const float* Wd0 = (const float*)d_in[14];
  const float* bd0 = (const float*)d_in[15];
  const float* Wd1 = (const float*)d_in[16];
  const float* bd1 = (const float*)d_in[17];
  const float* gam = (const float*)d_in[18];
  const float* bet = (const float*)d_in[19];
  const float* Wo1 = (const float*)d_in[20];
  const float* bo1 = (const float*)d_in[21];
  const float* Wo2 = (const float*)d_in[22];
  const float* bo2 = (const float*)d_in[23];

  const int* srcp = ei;
  const int* dstp = ei + NE;

  float* fv   = (float*)d_ws;                  // NV*8
  float* fe   = fv + (size_t)NV * 8;           // NE*8
  float* hb   = fe + (size_t)NE * 8;           // NG*64
  float* mu   = hb + NG * 64;                  // 64
  float* rstd = mu + 64;                       // 64

  hipLaunchKernelGGL(k_vertex_mlp, dim3(NV / 32), dim3(256), 0, stream,
                     x, W1, b1, W2, b2, fv);
  hipLaunchKernelGGL(k_edge_mlp, dim3(NE / 32), dim3(256), 0, stream,
                     x, pos, srcp, dstp, We1, be1, We2, be2, fe);
  hipLaunchKernelGGL(k_graph_reduce, dim3(NG), dim3(256), 0, stream,
                     fv, fe, srcp, dstp, Wd0, bd0, Wd1, bd1, hb);
  hipLaunchKernelGGL(k_bn_stats, dim3(1), dim3(256), 0, stream, hb, mu, rstd);
  hipLaunchKernelGGL(k_out_mlp, dim3(NG / 16), dim3(256), 0, stream,
                     hb, mu, rstd, gam, bet, Wo1, bo1, Wo2, bo2, (float*)d_out);
}